// Round 12
// baseline (38.983 us; speedup 1.0000x reference)
//
#include <hip/hip_runtime.h>

#define NN 128   // modes

// ---- whole-wave lane shifts via DPP (wave_shl:1 / wave_shr:1) ----
// bound_ctrl=false + old=src: edge lanes keep own value (zeroed by es coeff).
__device__ __forceinline__ float wshl1(float x) {   // lane i <- lane i+1
    return __int_as_float(__builtin_amdgcn_update_dpp(
        __float_as_int(x), __float_as_int(x), 0x130, 0xf, 0xf, false));
}
__device__ __forceinline__ float wshr1(float x) {   // lane i <- lane i-1
    return __int_as_float(__builtin_amdgcn_update_dpp(
        __float_as_int(x), __float_as_int(x), 0x138, 0xf, 0xf, false));
}

__device__ __forceinline__ float2 cmuladd(float2 acc, float2 x, float2 y) {
    acc.x += x.x * y.x - x.y * y.y;
    acc.y += x.x * y.y + x.y * y.x;
    return acc;
}

// ---------------- kernel 1: (cos,sin) table ----------------
// tab[j*128+m] = (cos th, sin th), th = theta_even[j,m]  (261 KB)
__global__ __launch_bounds__(256) void coef_kernel(
    const float* __restrict__ th_ev, float2* __restrict__ tab)
{
    int i = blockIdx.x * 256 + threadIdx.x;
    if (i < 255 * 128) {
        float s, c;
        __sincosf(th_ev[i], &s, &c);
        tab[i] = make_float2(c, s);
    }
}

// ---- 127-layer mesh evolution, layers J0..J0+126, R11 ring body ----
// Lane l holds rows 4l..4l+3 (4 complex). One float4 table load per layer,
// 8-deep explicit prefetch ring. Cross applied when global j is even
// (compile-time per slot since parity(j)=parity(J0+slot)).
template<int J0>
__device__ __forceinline__ void run127(const float4* __restrict__ TL, const int l,
                                       float2& v0, float2& v1, float2& v2, float2& v3,
                                       float4& thLast)
{
    const float A  = sqrtf(0.95f * 0.505f);
    const float B  = sqrtf(0.95f * 0.495f);
    const float C2 = sqrtf(0.98f * 0.01f);
    const float S2 = sqrtf(0.98f * 0.99f);
    const float ec0 = (l == 0)  ? S2 : C2, es0 = (l == 0)  ? 0.f : S2;
    const float ec3 = (l == 63) ? S2 : C2, es3 = (l == 63) ? 0.f : S2;

    float4 tb0 = TL[(J0+0)*64], tb1 = TL[(J0+1)*64], tb2 = TL[(J0+2)*64],
           tb3 = TL[(J0+3)*64], tb4 = TL[(J0+4)*64], tb5 = TL[(J0+5)*64],
           tb6 = TL[(J0+6)*64], tb7 = TL[(J0+7)*64];

    auto layer = [&](float4 t) {
        float rx = t.x * v0.x - t.y * v0.y;     // e^{i th} * v0
        float ry = t.x * v0.y + t.y * v0.x;
        float qx = t.z * v2.x - t.w * v2.y;     // e^{i th'} * v2
        float qy = t.z * v2.y + t.w * v2.x;
        float2 n0, n1, n2, n3;
        n0.x = A * rx   - B * v1.y;  n0.y = A * ry   + B * v1.x;
        n1.x = A * v1.x - B * ry;    n1.y = A * v1.y + B * rx;
        n2.x = A * qx   - B * v3.y;  n2.y = A * qy   + B * v3.x;
        n3.x = A * v3.x - B * qy;    n3.y = A * v3.y + B * qx;
        v0 = n0; v1 = n1; v2 = n2; v3 = n3;
    };
    auto crossl = [&]() {
        float nx = wshl1(v0.x), ny = wshl1(v0.y);   // lane l+1's v0
        float px = wshr1(v3.x), py = wshr1(v3.y);   // lane l-1's v3
        float2 m0, m1, m2, m3;
        m0.x = ec0 * v0.x - es0 * py;  m0.y = ec0 * v0.y + es0 * px;
        m3.x = ec3 * v3.x - es3 * ny;  m3.y = ec3 * v3.y + es3 * nx;
        m1.x = C2 * v1.x - S2 * v2.y;  m1.y = C2 * v1.y + S2 * v2.x;
        m2.x = C2 * v2.x - S2 * v1.y;  m2.y = C2 * v2.y + S2 * v1.x;
        v0 = m0; v1 = m1; v2 = m2; v3 = m3;
    };

    // 15 batches of 8: layers J0..J0+119; prefetch ≤ J0+127 ≤ 254 (no clamp)
    for (int j8 = J0; j8 < J0 + 120; j8 += 8) {
        { float4 t = tb0; tb0 = TL[(j8+ 8)*64]; layer(t); if (((J0+0)&1)==0) crossl(); }
        { float4 t = tb1; tb1 = TL[(j8+ 9)*64]; layer(t); if (((J0+1)&1)==0) crossl(); }
        { float4 t = tb2; tb2 = TL[(j8+10)*64]; layer(t); if (((J0+2)&1)==0) crossl(); }
        { float4 t = tb3; tb3 = TL[(j8+11)*64]; layer(t); if (((J0+3)&1)==0) crossl(); }
        { float4 t = tb4; tb4 = TL[(j8+12)*64]; layer(t); if (((J0+4)&1)==0) crossl(); }
        { float4 t = tb5; tb5 = TL[(j8+13)*64]; layer(t); if (((J0+5)&1)==0) crossl(); }
        { float4 t = tb6; tb6 = TL[(j8+14)*64]; layer(t); if (((J0+6)&1)==0) crossl(); }
        { float4 t = tb7; tb7 = TL[(j8+15)*64]; layer(t); if (((J0+7)&1)==0) crossl(); }
    }
    // tail: layers J0+120..J0+126 from slots 0..6
    layer(tb0); if (((J0+0)&1)==0) crossl();
    layer(tb1); if (((J0+1)&1)==0) crossl();
    layer(tb2); if (((J0+2)&1)==0) crossl();
    layer(tb3); if (((J0+3)&1)==0) crossl();
    layer(tb4); if (((J0+4)&1)==0) crossl();
    layer(tb5); if (((J0+5)&1)==0) crossl();
    layer(tb6); if (((J0+6)&1)==0) crossl();
    thLast = tb7;                     // theta[J0+127]
}

// ---------------- kernel 2: both phases in one grid ----------------
// blocks 0..127   : phase A, column c through layers 0..126 -> M1T[c][g]
// blocks 128..383 : phase B, basis column g through layers 127..253 +
//                   diag(th254)+MMI_OUT fold -> T2T[g][n]
__global__ __launch_bounds__(64) void phase_kernel(
    const float4* __restrict__ tab,        // (255*64) float4 rows
    const float* __restrict__ theta_in,    // (128,)
    float2* __restrict__ M1T,              // [128][256]
    float2* __restrict__ T2T)              // [256][128]
{
    const int bid = blockIdx.x;
    const int l = threadIdx.x;
    const float A = sqrtf(0.95f * 0.505f);
    const float B = sqrtf(0.95f * 0.495f);
    const float4* TL = tab + l;

    float2 v0 = make_float2(0.f, 0.f), v1 = v0, v2 = v0, v3 = v0;
    float4 thLast;

    if (bid < 128) {
        const int c = bid;
        // init: MMI_IN * diag(d_in): rows 2c: A e^{i th}, 2c+1: iB e^{i th}
        float s, co;
        __sincosf(theta_in[c], &s, &co);
        if (l == (c >> 1)) {
            float2 e0 = make_float2(A * co, A * s);
            float2 e1 = make_float2(-B * s, B * co);
            if (c & 1) { v2 = e0; v3 = e1; }
            else       { v0 = e0; v1 = e1; }
        }
        run127<0>(TL, l, v0, v1, v2, v3, thLast);
        // store column c of M1 (rows 4l..4l+3), contiguous in g
        float4* dst = (float4*)(M1T + (size_t)c * 256 + 4 * l);
        dst[0] = make_float4(v0.x, v0.y, v1.x, v1.y);
        dst[1] = make_float4(v2.x, v2.y, v3.x, v3.y);
    } else {
        const int g = bid - 128;
        // init: basis vector e_g
        if (l == (g >> 2)) {
            float2 one = make_float2(1.f, 0.f);
            int k = g & 3;
            if      (k == 0) v0 = one;
            else if (k == 1) v1 = one;
            else if (k == 2) v2 = one;
            else             v3 = one;
        }
        run127<127>(TL, l, v0, v1, v2, v3, thLast);
        // epilogue: diag(theta[254]) + MMI_OUT fold -> rows 2l, 2l+1 of T2
        float rx = thLast.x * v0.x - thLast.y * v0.y;
        float ry = thLast.x * v0.y + thLast.y * v0.x;
        float qx = thLast.z * v2.x - thLast.w * v2.y;
        float qy = thLast.z * v2.y + thLast.w * v2.x;
        float4 o;
        o.x = A * rx - B * v1.y;  o.y = A * ry + B * v1.x;   // row 2l
        o.z = A * qx - B * v3.y;  o.w = A * qy + B * v3.x;   // row 2l+1
        *(float4*)(T2T + (size_t)g * 128 + 2 * l) = o;
    }
}

// ---------------- kernel 3: combine + epilogue ----------------
// out[n][c] = Re( e^{i th_out[n]} * sum_g T2[n][g] * M1[g][c] )
// block = column c (128 blocks, 64 lanes); lane l -> rows 2l, 2l+1.
__global__ __launch_bounds__(64) void combine_kernel(
    const float2* __restrict__ M1T,        // [128][256]
    const float2* __restrict__ T2T,        // [256][128]
    const float* __restrict__ theta_out,   // (128,)
    float* __restrict__ out)               // (128,128)
{
    const int c = blockIdx.x;
    const int l = threadIdx.x;
    const float2* m1 = M1T + (size_t)c * 256;

    float2 acc0 = make_float2(0.f, 0.f), acc1 = acc0;
    #pragma unroll 8
    for (int g = 0; g < 256; ++g) {
        float2 m = m1[g];                                   // wave-uniform
        float4 t = *(const float4*)(T2T + (size_t)g * 128 + 2 * l);  // coalesced
        acc0 = cmuladd(acc0, make_float2(t.x, t.y), m);
        acc1 = cmuladd(acc1, make_float2(t.z, t.w), m);
    }

    float2 tho = ((const float2*)theta_out)[l];
    float s0, c0, s1, c1;
    __sincosf(tho.x, &s0, &c0);
    __sincosf(tho.y, &s1, &c1);
    out[(2 * l)     * NN + c] = c0 * acc0.x - s0 * acc0.y;
    out[(2 * l + 1) * NN + c] = c1 * acc1.x - s1 * acc1.y;
}

// ---------------- fallback (proven R6-style): ws too small ----------------
struct CoefF { float2 a0, b0, a1, b1; };
__device__ __forceinline__ CoefF make_coef_f(float2 th) {
    const float A = sqrtf(0.95f * 0.505f);
    const float B = sqrtf(0.95f * 0.495f);
    float s0, c0, s1, c1;
    __sincosf(th.x, &s0, &c0);
    __sincosf(th.y, &s1, &c1);
    CoefF cf;
    cf.a0 = make_float2(A * c0, A * s0); cf.b0 = make_float2(-B * s0, B * c0);
    cf.a1 = make_float2(A * c1, A * s1); cf.b1 = make_float2(-B * s1, B * c1);
    return cf;
}
__global__ __launch_bounds__(64) void mesh_fallback(
    const float* __restrict__ theta_in, const float* __restrict__ theta_even,
    const float* __restrict__ theta_out, float* __restrict__ out)
{
    const int c = blockIdx.x, l = threadIdx.x;
    const float A  = sqrtf(0.95f * 0.505f);
    const float B  = sqrtf(0.95f * 0.495f);
    const float C2 = sqrtf(0.98f * 0.01f);
    const float S2 = sqrtf(0.98f * 0.99f);
    const float ec0 = (l == 0)  ? S2 : C2, es0 = (l == 0)  ? 0.f : S2;
    const float ec3 = (l == 63) ? S2 : C2, es3 = (l == 63) ? 0.f : S2;
    float2 v0 = make_float2(0.f, 0.f), v1 = v0, v2 = v0, v3 = v0;
    {
        float s, co; __sincosf(theta_in[c], &s, &co);
        if (l == (c >> 1)) {
            float2 e0 = make_float2(A * co, A * s), e1 = make_float2(-B * s, B * co);
            if (c & 1) { v2 = e0; v3 = e1; } else { v0 = e0; v1 = e1; }
        }
    }
    const float2* tev = (const float2*)theta_even + l;
    for (int j = 0; j < 254; ++j) {
        CoefF cf = make_coef_f(tev[j * 64]);
        float2 n0, n1, n2, n3;
        n0.x = cf.a0.x*v0.x - cf.a0.y*v0.y - B*v1.y;  n0.y = cf.a0.x*v0.y + cf.a0.y*v0.x + B*v1.x;
        n1.x = cf.b0.x*v0.x - cf.b0.y*v0.y + A*v1.x;  n1.y = cf.b0.x*v0.y + cf.b0.y*v0.x + A*v1.y;
        n2.x = cf.a1.x*v2.x - cf.a1.y*v2.y - B*v3.y;  n2.y = cf.a1.x*v2.y + cf.a1.y*v2.x + B*v3.x;
        n3.x = cf.b1.x*v2.x - cf.b1.y*v2.y + A*v3.x;  n3.y = cf.b1.x*v2.y + cf.b1.y*v2.x + A*v3.y;
        v0 = n0; v1 = n1; v2 = n2; v3 = n3;
        if ((j & 1) == 0) {
            float nx = wshl1(v0.x), ny = wshl1(v0.y);
            float px = wshr1(v3.x), py = wshr1(v3.y);
            float2 m0, m1, m2, m3;
            m0.x = ec0*v0.x - es0*py;  m0.y = ec0*v0.y + es0*px;
            m3.x = ec3*v3.x - es3*ny;  m3.y = ec3*v3.y + es3*nx;
            m1.x = C2*v1.x - S2*v2.y;  m1.y = C2*v1.y + S2*v2.x;
            m2.x = C2*v2.x - S2*v1.y;  m2.y = C2*v2.y + S2*v1.x;
            v0 = m0; v1 = m1; v2 = m2; v3 = m3;
        }
    }
    CoefF cf = make_coef_f(tev[254 * 64]);
    float2 o0, o1;
    o0.x = cf.a0.x*v0.x - cf.a0.y*v0.y - B*v1.y;  o0.y = cf.a0.x*v0.y + cf.a0.y*v0.x + B*v1.x;
    o1.x = cf.a1.x*v2.x - cf.a1.y*v2.y - B*v3.y;  o1.y = cf.a1.x*v2.y + cf.a1.y*v2.x + B*v3.x;
    float2 tho = ((const float2*)theta_out)[l];
    float s0, c0, s1, c1;
    __sincosf(tho.x, &s0, &c0);
    __sincosf(tho.y, &s1, &c1);
    out[(2 * l)     * NN + c] = c0 * o0.x - s0 * o0.y;
    out[(2 * l + 1) * NN + c] = c1 * o1.x - s1 * o1.y;
}

extern "C" void kernel_launch(void* const* d_in, const int* in_sizes, int n_in,
                              void* d_out, int out_size, void* d_ws, size_t ws_size,
                              hipStream_t stream) {
    // Identify inputs by SIZE: theta_even is the unique large (32640) array;
    // the two 128-elem arrays keep relative order (theta_in before theta_out).
    int ev = 0;
    for (int i = 0; i < n_in; ++i) if (in_sizes[i] > 1000) ev = i;
    int a = -1, b = -1;
    for (int i = 0; i < n_in; ++i) {
        if (i == ev) continue;
        if (a < 0) a = i; else if (b < 0) b = i;
    }
    const float* th_in  = (const float*)d_in[a];
    const float* th_ev  = (const float*)d_in[ev];
    const float* th_out = (const float*)d_in[b];

    // ws layout: M1T (256 KB) | T2T (256 KB) | tab (261120 B)
    const size_t m1_bytes  = (size_t)128 * 256 * sizeof(float2);   // 262144
    const size_t t2_bytes  = (size_t)256 * 128 * sizeof(float2);   // 262144
    const size_t tab_bytes = (size_t)255 * 128 * sizeof(float2);   // 261120
    if (ws_size >= m1_bytes + t2_bytes + tab_bytes) {
        float2* M1T = (float2*)d_ws;
        float2* T2T = (float2*)((char*)d_ws + m1_bytes);
        float2* tab = (float2*)((char*)d_ws + m1_bytes + t2_bytes);
        coef_kernel<<<dim3(128), dim3(256), 0, stream>>>(th_ev, tab);
        phase_kernel<<<dim3(384), dim3(64), 0, stream>>>(
            (const float4*)tab, th_in, M1T, T2T);
        combine_kernel<<<dim3(128), dim3(64), 0, stream>>>(
            M1T, T2T, th_out, (float*)d_out);
    } else {
        mesh_fallback<<<dim3(NN), dim3(64), 0, stream>>>(th_in, th_ev, th_out, (float*)d_out);
    }
}

// Round 13
// 38.328 us; speedup vs baseline: 1.0171x; 1.0171x over previous
//
#include <hip/hip_runtime.h>

#define NN 128     // modes
#define CHUNK 32   // layers staged per LDS buffer
#define NCH 8      // 8 chunks x 32 = 256 staged rows (row 255 clamped to 254)

typedef const __attribute__((address_space(1))) void* gptr_t;
typedef __attribute__((address_space(3))) void* lptr_t;

// ---- whole-wave lane shifts via DPP (wave_shl:1 / wave_shr:1), proven R9/R11 ----
__device__ __forceinline__ float wshl1(float x) {   // lane i <- lane i+1
    return __int_as_float(__builtin_amdgcn_update_dpp(
        __float_as_int(x), __float_as_int(x), 0x130, 0xf, 0xf, false));
}
__device__ __forceinline__ float wshr1(float x) {   // lane i <- lane i-1
    return __int_as_float(__builtin_amdgcn_update_dpp(
        __float_as_int(x), __float_as_int(x), 0x138, 0xf, 0xf, false));
}

// ---------------- kernel 1: (cos,sin) table ----------------
// tab[j*128+m] = (cos th, sin th), th = theta_even[j,m]  (261 KB in d_ws)
__global__ __launch_bounds__(256) void coef_kernel(
    const float* __restrict__ th_ev, float2* __restrict__ tab)
{
    int i = blockIdx.x * 256 + threadIdx.x;
    if (i < 255 * 128) {
        float s, c;
        __sincosf(th_ev[i], &s, &c);
        tab[i] = make_float2(c, s);
    }
}

// ---------------- kernel 2: mesh evolution, LDS-staged table ----------------
// One wave per column c (128 blocks). Lane l holds rows 4l..4l+3 (4 complex).
// Table staged global->LDS in 32-layer chunks via global_load_lds (16B/lane),
// double-buffered, counted vmcnt waits, zero barriers (single wave).
// Inner loop: 1 ds_read_b128 + ~24 VALU per layer.
__global__ __launch_bounds__(64) void mesh_lds_kernel(
    const float4* __restrict__ tab,        // (255*64) float4 rows: (c0,s0,c1,s1)
    const float* __restrict__ theta_in,    // (128,)
    const float* __restrict__ theta_out,   // (128,)
    float* __restrict__ out)               // (128,128) f32 = Re(arch)
{
    __shared__ float4 lbuf[2][CHUNK][64];  // 64 KB

    const int c = blockIdx.x;
    const int l = threadIdx.x;

    const float A  = sqrtf(0.95f * 0.505f);
    const float B  = sqrtf(0.95f * 0.495f);
    const float C2 = sqrtf(0.98f * 0.01f);
    const float S2 = sqrtf(0.98f * 0.99f);

    // branchless corner coeffs: row 0 (l==0, slot v0), row 255 (l==63, slot v3)
    const float ec0 = (l == 0)  ? S2 : C2, es0 = (l == 0)  ? 0.f : S2;
    const float ec3 = (l == 63) ? S2 : C2, es3 = (l == 63) ? 0.f : S2;

    // stage chunk ch into buffer nb: rows ch*32..ch*32+31 (clamped at 254)
    auto stage = [&](int ch, int nb) {
        #pragma unroll
        for (int s = 0; s < CHUNK; ++s) {
            int j = ch * CHUNK + s;
            if (j > 254) j = 254;
            __builtin_amdgcn_global_load_lds(
                (gptr_t)(tab + j * 64 + l),          // per-lane global src (16B)
                (lptr_t)(&lbuf[nb][s][0]),           // wave-uniform LDS base
                16, 0, 0);                           // lane l lands at base+l*16
        }
    };

    stage(0, 0);   // chunk 0 in flight while we init state below

    // init: column c after MMI_IN -> rows 2c: A e^{i th}, 2c+1: iB e^{i th}
    float2 v0 = make_float2(0.f, 0.f), v1 = v0, v2 = v0, v3 = v0;
    {
        float s, co;
        __sincosf(theta_in[c], &s, &co);
        float2 e0 = make_float2(A * co, A * s);
        float2 e1 = make_float2(-B * s, B * co);
        if (l == (c >> 1)) {
            if (c & 1) { v2 = e0; v3 = e1; }
            else       { v0 = e0; v1 = e1; }
        }
    }

    // rotate-then-mix layer (proven R11 math)
    auto layer = [&](float4 t) {
        float rx = t.x * v0.x - t.y * v0.y;     // e^{i th} * v0
        float ry = t.x * v0.y + t.y * v0.x;
        float qx = t.z * v2.x - t.w * v2.y;     // e^{i th'} * v2
        float qy = t.z * v2.y + t.w * v2.x;
        float2 n0, n1, n2, n3;
        n0.x = A * rx   - B * v1.y;  n0.y = A * ry   + B * v1.x;
        n1.x = A * v1.x - B * ry;    n1.y = A * v1.y + B * rx;
        n2.x = A * qx   - B * v3.y;  n2.y = A * qy   + B * v3.x;
        n3.x = A * v3.x - B * qy;    n3.y = A * v3.y + B * qx;
        v0 = n0; v1 = n1; v2 = n2; v3 = n3;
    };
    auto crossl = [&]() {
        float nx = wshl1(v0.x), ny = wshl1(v0.y);   // lane l+1's v0
        float px = wshr1(v3.x), py = wshr1(v3.y);   // lane l-1's v3
        float2 m0, m1, m2, m3;
        m0.x = ec0 * v0.x - es0 * py;  m0.y = ec0 * v0.y + es0 * px;
        m3.x = ec3 * v3.x - es3 * ny;  m3.y = ec3 * v3.y + es3 * nx;
        m1.x = C2 * v1.x - S2 * v2.y;  m1.y = C2 * v1.y + S2 * v2.x;
        m2.x = C2 * v2.x - S2 * v1.y;  m2.y = C2 * v2.y + S2 * v1.x;
        v0 = m0; v1 = m1; v2 = m2; v3 = m3;
    };

    float2 o0, o1;
    for (int ch = 0; ch < NCH; ++ch) {
        const int buf = ch & 1;
        if (ch + 1 < NCH) {
            stage(ch + 1, buf ^ 1);                       // prefetch next chunk
            asm volatile("s_waitcnt vmcnt(32)" ::: "memory");  // this chunk done
        } else {
            asm volatile("s_waitcnt vmcnt(0)" ::: "memory");
        }
        __builtin_amdgcn_sched_barrier(0);

        if (ch + 1 < NCH) {
            // 32 full layers; global j = ch*32+s, parity(j)=parity(s)
            #pragma unroll
            for (int s = 0; s < CHUNK; ++s) {
                float4 t = lbuf[buf][s][l];
                layer(t);
                if ((s & 1) == 0) crossl();
            }
        } else {
            // last chunk: layers 224..253 (slots 0..29), slot 30 = theta[254] fold
            #pragma unroll
            for (int s = 0; s < 30; ++s) {
                float4 t = lbuf[buf][s][l];
                layer(t);
                if ((s & 1) == 0) crossl();
            }
            float4 t254 = lbuf[buf][30][l];
            float rx = t254.x * v0.x - t254.y * v0.y;
            float ry = t254.x * v0.y + t254.y * v0.x;
            float qx = t254.z * v2.x - t254.w * v2.y;
            float qy = t254.z * v2.y + t254.w * v2.x;
            o0.x = A * rx - B * v1.y;  o0.y = A * ry + B * v1.x;   // row 2l
            o1.x = A * qx - B * v3.y;  o1.y = A * qy + B * v3.x;   // row 2l+1
        }
    }

    // diag(d_out) rotation, keep real part
    float2 tho = ((const float2*)theta_out)[l];
    float s0, c0, s1, c1;
    __sincosf(tho.x, &s0, &c0);
    __sincosf(tho.y, &s1, &c1);
    out[(2 * l)     * NN + c] = c0 * o0.x - s0 * o0.y;
    out[(2 * l + 1) * NN + c] = c1 * o1.x - s1 * o1.y;
}

// ---------------- fallback (proven R6-style): ws too small ----------------
struct CoefF { float2 a0, b0, a1, b1; };
__device__ __forceinline__ CoefF make_coef_f(float2 th) {
    const float A = sqrtf(0.95f * 0.505f);
    const float B = sqrtf(0.95f * 0.495f);
    float s0, c0, s1, c1;
    __sincosf(th.x, &s0, &c0);
    __sincosf(th.y, &s1, &c1);
    CoefF cf;
    cf.a0 = make_float2(A * c0, A * s0); cf.b0 = make_float2(-B * s0, B * c0);
    cf.a1 = make_float2(A * c1, A * s1); cf.b1 = make_float2(-B * s1, B * c1);
    return cf;
}
__global__ __launch_bounds__(64) void mesh_fallback(
    const float* __restrict__ theta_in, const float* __restrict__ theta_even,
    const float* __restrict__ theta_out, float* __restrict__ out)
{
    const int c = blockIdx.x, l = threadIdx.x;
    const float A  = sqrtf(0.95f * 0.505f);
    const float B  = sqrtf(0.95f * 0.495f);
    const float C2 = sqrtf(0.98f * 0.01f);
    const float S2 = sqrtf(0.98f * 0.99f);
    const float ec0 = (l == 0)  ? S2 : C2, es0 = (l == 0)  ? 0.f : S2;
    const float ec3 = (l == 63) ? S2 : C2, es3 = (l == 63) ? 0.f : S2;
    float2 v0 = make_float2(0.f, 0.f), v1 = v0, v2 = v0, v3 = v0;
    {
        float s, co; __sincosf(theta_in[c], &s, &co);
        if (l == (c >> 1)) {
            float2 e0 = make_float2(A * co, A * s), e1 = make_float2(-B * s, B * co);
            if (c & 1) { v2 = e0; v3 = e1; } else { v0 = e0; v1 = e1; }
        }
    }
    const float2* tev = (const float2*)theta_even + l;
    for (int j = 0; j < 254; ++j) {
        CoefF cf = make_coef_f(tev[j * 64]);
        float2 n0, n1, n2, n3;
        n0.x = cf.a0.x*v0.x - cf.a0.y*v0.y - B*v1.y;  n0.y = cf.a0.x*v0.y + cf.a0.y*v0.x + B*v1.x;
        n1.x = cf.b0.x*v0.x - cf.b0.y*v0.y + A*v1.x;  n1.y = cf.b0.x*v0.y + cf.b0.y*v0.x + A*v1.y;
        n2.x = cf.a1.x*v2.x - cf.a1.y*v2.y - B*v3.y;  n2.y = cf.a1.x*v2.y + cf.a1.y*v2.x + B*v3.x;
        n3.x = cf.b1.x*v2.x - cf.b1.y*v2.y + A*v3.x;  n3.y = cf.b1.x*v2.y + cf.b1.y*v2.x + A*v3.y;
        v0 = n0; v1 = n1; v2 = n2; v3 = n3;
        if ((j & 1) == 0) {
            float nx = wshl1(v0.x), ny = wshl1(v0.y);
            float px = wshr1(v3.x), py = wshr1(v3.y);
            float2 m0, m1, m2, m3;
            m0.x = ec0*v0.x - es0*py;  m0.y = ec0*v0.y + es0*px;
            m3.x = ec3*v3.x - es3*ny;  m3.y = ec3*v3.y + es3*nx;
            m1.x = C2*v1.x - S2*v2.y;  m1.y = C2*v1.y + S2*v2.x;
            m2.x = C2*v2.x - S2*v1.y;  m2.y = C2*v2.y + S2*v1.x;
            v0 = m0; v1 = m1; v2 = m2; v3 = m3;
        }
    }
    CoefF cf = make_coef_f(tev[254 * 64]);
    float2 o0, o1;
    o0.x = cf.a0.x*v0.x - cf.a0.y*v0.y - B*v1.y;  o0.y = cf.a0.x*v0.y + cf.a0.y*v0.x + B*v1.x;
    o1.x = cf.a1.x*v2.x - cf.a1.y*v2.y - B*v3.y;  o1.y = cf.a1.x*v2.y + cf.a1.y*v2.x + B*v3.x;
    float2 tho = ((const float2*)theta_out)[l];
    float s0, c0, s1, c1;
    __sincosf(tho.x, &s0, &c0);
    __sincosf(tho.y, &s1, &c1);
    out[(2 * l)     * NN + c] = c0 * o0.x - s0 * o0.y;
    out[(2 * l + 1) * NN + c] = c1 * o1.x - s1 * o1.y;
}

extern "C" void kernel_launch(void* const* d_in, const int* in_sizes, int n_in,
                              void* d_out, int out_size, void* d_ws, size_t ws_size,
                              hipStream_t stream) {
    // Identify inputs by SIZE: theta_even is the unique large (32640) array;
    // the two 128-elem arrays keep relative order (theta_in before theta_out).
    int ev = 0;
    for (int i = 0; i < n_in; ++i) if (in_sizes[i] > 1000) ev = i;
    int a = -1, b = -1;
    for (int i = 0; i < n_in; ++i) {
        if (i == ev) continue;
        if (a < 0) a = i; else if (b < 0) b = i;
    }
    const float* th_in  = (const float*)d_in[a];
    const float* th_ev  = (const float*)d_in[ev];
    const float* th_out = (const float*)d_in[b];

    const size_t tab_bytes = (size_t)255 * 128 * sizeof(float2);   // 261120
    if (ws_size >= tab_bytes) {
        float2* tab = (float2*)d_ws;
        coef_kernel<<<dim3(128), dim3(256), 0, stream>>>(th_ev, tab);
        mesh_lds_kernel<<<dim3(NN), dim3(64), 0, stream>>>(
            (const float4*)tab, th_in, th_out, (float*)d_out);
    } else {
        mesh_fallback<<<dim3(NN), dim3(64), 0, stream>>>(th_in, th_ev, th_out, (float*)d_out);
    }
}